// Round 1
// baseline (1408.176 us; speedup 1.0000x reference)
//
#include <hip/hip_runtime.h>
#include <stdint.h>

typedef unsigned short u16;
typedef unsigned int u32;
typedef __attribute__((ext_vector_type(8))) short bf16x8;
typedef __attribute__((ext_vector_type(4))) float f32x4;

#define NTOK 8192
#define DDIM 1024
#define HDIM 4096
#define NEXP 8
#define KSEL 4
#define TILE 128
#define BK 32
#define LISTCAP 8192

// ---------- helpers ----------
__device__ __forceinline__ u16 f2bf(float f) {
  union { float f; u32 u; } v; v.f = f;
  u32 r = v.u + 0x7fffu + ((v.u >> 16) & 1u);   // RNE
  return (u16)(r >> 16);
}

__device__ __forceinline__ void gl_lds16(const void* g, void* l) {
  // async global->LDS, 16B per lane; LDS dest is wave-uniform base + lane*16
  __builtin_amdgcn_global_load_lds(
      (__attribute__((address_space(1))) u32*)(uintptr_t)g,
      (__attribute__((address_space(3))) u32*)l, 16, 0, 0);
}

__device__ __forceinline__ float gelu_t(float x) {
  // tanh-approx gelu (flax default)
  float u = 0.7978845608028654f * (x + 0.044715f * x * x * x);
  float e = __expf(2.0f * u);
  float th = 1.0f - 2.0f / (e + 1.0f);          // overflow-safe tanh
  return 0.5f * x * (1.0f + th);
}

// ---------- x -> bf16 ----------
__global__ void k_cvt_x(const float* __restrict__ x, u16* __restrict__ xb) {
  int i = blockIdx.x * blockDim.x + threadIdx.x;      // one float4 per thread
  float4 v = ((const float4*)x)[i];
  uint2 p;
  p.x = (u32)f2bf(v.x) | ((u32)f2bf(v.y) << 16);
  p.y = (u32)f2bf(v.z) | ((u32)f2bf(v.w) << 16);
  ((uint2*)xb)[i] = p;
}

// ---------- weight transpose + convert: in [E][R][C] f32 -> out [E][C][R] bf16 ----------
__global__ void k_transpose_bf16(const float* __restrict__ in, u16* __restrict__ out,
                                 int R, int C) {
  __shared__ float tile[32][33];
  int e = blockIdx.z;
  const float* src = in + (size_t)e * R * C;
  u16* dst = out + (size_t)e * R * C;
  int c0 = blockIdx.x * 32, r0 = blockIdx.y * 32;
  int tx = threadIdx.x, ty = threadIdx.y;
#pragma unroll
  for (int i = 0; i < 4; i++)
    tile[ty + i * 8][tx] = src[(size_t)(r0 + ty + i * 8) * C + c0 + tx];
  __syncthreads();
#pragma unroll
  for (int i = 0; i < 4; i++)
    dst[(size_t)(c0 + ty + i * 8) * R + r0 + tx] = f2bf(tile[tx][ty + i * 8]);
}

// ---------- router: logits (fp32), top-4, normalized weights, expert lists ----------
__global__ void k_router(const float* __restrict__ x, const float* __restrict__ rw,
                         int* __restrict__ counts, int* __restrict__ tok_list,
                         float* __restrict__ w_list) {
  int token = blockIdx.x * 4 + (threadIdx.x >> 6);
  int lane = threadIdx.x & 63;
  const float* xr = x + (size_t)token * DDIM;
  float p[NEXP];
#pragma unroll
  for (int e = 0; e < NEXP; e++) p[e] = 0.f;
  for (int it = 0; it < DDIM / 64; ++it) {
    int j = it * 64 + lane;
    float xj = xr[j];
    const float* r = rw + (size_t)j * NEXP;
    float4 a = *(const float4*)r;
    float4 b = *(const float4*)(r + 4);
    p[0] += xj * a.x; p[1] += xj * a.y; p[2] += xj * a.z; p[3] += xj * a.w;
    p[4] += xj * b.x; p[5] += xj * b.y; p[6] += xj * b.z; p[7] += xj * b.w;
  }
#pragma unroll
  for (int off = 32; off; off >>= 1) {
#pragma unroll
    for (int e = 0; e < NEXP; e++) p[e] += __shfl_xor(p[e], off);
  }
  // all 64 lanes now hold identical logits; stable top-4 (lowest index wins ties)
  unsigned used = 0;
  int idx[KSEL]; float lg[KSEL];
#pragma unroll
  for (int k = 0; k < KSEL; k++) {
    float bv = -1e30f; int bi = 0;
#pragma unroll
    for (int e = 0; e < NEXP; e++)
      if (!((used >> e) & 1) && p[e] > bv) { bv = p[e]; bi = e; }
    used |= 1u << bi; idx[k] = bi; lg[k] = bv;
  }
  float wv[KSEL]; float wsum = 0.f;
#pragma unroll
  for (int k = 0; k < KSEL; k++) { wv[k] = __expf(lg[k] - lg[0]); wsum += wv[k]; }
  float inv = 1.f / wsum;
  if (lane < KSEL) {
    int e = idx[lane];
    int pos = atomicAdd(&counts[e], 1);
    tok_list[e * LISTCAP + pos] = token;
    w_list[e * LISTCAP + pos] = wv[lane] * inv;
  }
}

// ---------- grouped GEMM (m97-lineage 128x128 tile, 4 waves, BK=32) ----------
// IS_UP:  A=xb (gathered rows via tok_list), B=upbT[e] [H][D], epilogue gelu->act(bf16)
// !IS_UP: A=act (linear), B=downbT[e] [D][H], split-K via blockIdx.z,
//         epilogue atomicAdd(w * acc) into out
template <bool IS_UP>
__global__ __launch_bounds__(256) void k_moe_gemm(
    const u16* __restrict__ A, const u16* __restrict__ B,
    const int* __restrict__ tok_list, const float* __restrict__ w_list,
    const int* __restrict__ counts_e,
    u16* __restrict__ actOut, float* __restrict__ out) {
  const int cnt = *counts_e;
  const int mtile = blockIdx.y;
  if (mtile * TILE >= cnt) return;
  const int ntile = blockIdx.x;
  const int K = IS_UP ? DDIM : HDIM;
  const int kspan = IS_UP ? DDIM : HDIM / 2;
  const int kbeg = blockIdx.z * kspan;

  __shared__ u16 As[TILE * BK];
  __shared__ u16 Bs[TILE * BK];

  const int t = threadIdx.x, lane = t & 63, wave = t >> 6;
  const int ar = t >> 2, akb = (t & 3) * 8;
  int row0, row1;
  if (IS_UP) {
    row0 = tok_list[mtile * TILE + ar];
    row1 = tok_list[mtile * TILE + ar + 64];
  } else {
    row0 = mtile * TILE + ar;
    row1 = row0 + 64;
  }
  const u16* gA0 = A + (size_t)row0 * K + akb;
  const u16* gA1 = A + (size_t)row1 * K + akb;
  const int bn = ntile * TILE + ar;
  const u16* gB0 = B + (size_t)bn * K + akb;
  const u16* gB1 = gB0 + (size_t)64 * K;

  u16* AsW = As + wave * 512;   // wave-uniform LDS bases (1024B per wave)
  u16* BsW = Bs + wave * 512;

  f32x4 acc[4][4];
#pragma unroll
  for (int m = 0; m < 4; m++)
#pragma unroll
    for (int n = 0; n < 4; n++) acc[m][n] = (f32x4){0.f, 0.f, 0.f, 0.f};

  const int wm = wave >> 1, wn = wave & 1;
  const int fr = lane & 15, fk = (lane >> 4) * 8;

  for (int k0 = kbeg; k0 < kbeg + kspan; k0 += BK) {
    gl_lds16(gA0 + k0, AsW);
    gl_lds16(gA1 + k0, AsW + 2048);
    gl_lds16(gB0 + k0, BsW);
    gl_lds16(gB1 + k0, BsW + 2048);
    __syncthreads();   // compiler emits vmcnt(0) drain before barrier
    bf16x8 a[4], b[4];
#pragma unroll
    for (int m = 0; m < 4; m++) a[m] = *(const bf16x8*)&As[(wm * 64 + m * 16 + fr) * BK + fk];
#pragma unroll
    for (int n = 0; n < 4; n++) b[n] = *(const bf16x8*)&Bs[(wn * 64 + n * 16 + fr) * BK + fk];
#pragma unroll
    for (int m = 0; m < 4; m++)
#pragma unroll
      for (int n = 0; n < 4; n++)
        acc[m][n] = __builtin_amdgcn_mfma_f32_16x16x32_bf16(a[m], b[n], acc[m][n], 0, 0, 0);
    __syncthreads();
  }

  if (IS_UP) {
#pragma unroll
    for (int m = 0; m < 4; m++) {
#pragma unroll
      for (int j = 0; j < 4; j++) {
        int r = wm * 64 + m * 16 + (lane >> 4) * 4 + j;
        size_t rowoff = (size_t)(mtile * TILE + r) * HDIM + (size_t)ntile * TILE;
#pragma unroll
        for (int n = 0; n < 4; n++) {
          int c = wn * 64 + n * 16 + fr;
          actOut[rowoff + c] = f2bf(gelu_t(acc[m][n][j]));
        }
      }
    }
  } else {
#pragma unroll
    for (int m = 0; m < 4; m++) {
#pragma unroll
      for (int j = 0; j < 4; j++) {
        int r = wm * 64 + m * 16 + (lane >> 4) * 4 + j;
        int slot = mtile * TILE + r;
        if (slot < cnt) {
          int tok = tok_list[slot];
          float w = w_list[slot];
          float* orow = out + (size_t)tok * DDIM + (size_t)ntile * TILE;
#pragma unroll
          for (int n = 0; n < 4; n++) {
            int c = wn * 64 + n * 16 + fr;
            atomicAdd(&orow[c], w * acc[m][n][j]);
          }
        }
      }
    }
  }
}

// ---------- launch ----------
extern "C" void kernel_launch(void* const* d_in, const int* in_sizes, int n_in,
                              void* d_out, int out_size, void* d_ws, size_t ws_size,
                              hipStream_t stream) {
  const float* x  = (const float*)d_in[0];
  const float* rw = (const float*)d_in[1];
  const float* up = (const float*)d_in[2];
  const float* dw = (const float*)d_in[3];
  float* out = (float*)d_out;

  char* ws = (char*)d_ws;
  size_t off = 0;
  u16* xb = (u16*)(ws + off);      off += (size_t)NTOK * DDIM * 2;          // 16 MiB
  u16* upbT = (u16*)(ws + off);    off += (size_t)NEXP * HDIM * DDIM * 2;   // 64 MiB
  u16* downbT = (u16*)(ws + off);  off += (size_t)NEXP * DDIM * HDIM * 2;   // 64 MiB
  u16* act = (u16*)(ws + off);     off += (size_t)NTOK * HDIM * 2;          // 64 MiB
  int* counts = (int*)(ws + off);  off += 128;
  int* tok = (int*)(ws + off);     off += (size_t)NEXP * LISTCAP * 4;
  float* wl = (float*)(ws + off);  off += (size_t)NEXP * LISTCAP * 4;
  // total required ~209 MiB (assumed <= ws_size)

  // zero output (we accumulate atomically) + counts + token lists (padding -> token 0)
  hipMemsetAsync(d_out, 0, (size_t)NTOK * DDIM * 4, stream);
  hipMemsetAsync(counts, 0, 128 + (size_t)NEXP * LISTCAP * 4, stream);

  k_cvt_x<<<dim3(NTOK * DDIM / 4 / 256), dim3(256), 0, stream>>>(x, xb);
  // up_w [E][D][H] -> upbT [E][H][D]
  k_transpose_bf16<<<dim3(HDIM / 32, DDIM / 32, NEXP), dim3(32, 8), 0, stream>>>(up, upbT, DDIM, HDIM);
  // down_w [E][H][D] -> downbT [E][D][H]
  k_transpose_bf16<<<dim3(DDIM / 32, HDIM / 32, NEXP), dim3(32, 8), 0, stream>>>(dw, downbT, HDIM, DDIM);
  k_router<<<dim3(NTOK / 4), dim3(256), 0, stream>>>(x, rw, counts, tok, wl);

  for (int e = 0; e < NEXP; e++) {
    k_moe_gemm<true><<<dim3(HDIM / TILE, NTOK / TILE, 1), dim3(256), 0, stream>>>(
        xb, upbT + (size_t)e * HDIM * DDIM, tok + e * LISTCAP, nullptr, counts + e, act, nullptr);
    k_moe_gemm<false><<<dim3(DDIM / TILE, NTOK / TILE, 2), dim3(256), 0, stream>>>(
        act, downbT + (size_t)e * DDIM * HDIM, tok + e * LISTCAP, wl + e * LISTCAP, counts + e,
        nullptr, out);
  }
}

// Round 2
// 1079.041 us; speedup vs baseline: 1.3050x; 1.3050x over previous
//
#include <hip/hip_runtime.h>
#include <stdint.h>

typedef unsigned short u16;
typedef unsigned int u32;
typedef __attribute__((ext_vector_type(8))) short bf16x8;
typedef __attribute__((ext_vector_type(4))) float f32x4;

#define NTOK 8192
#define DDIM 1024
#define HDIM 4096
#define NEXP 8
#define KSEL 4
#define TILE 128
#define BK 32
#define SLOTCAP 33792   // 32768 assignments + per-expert pad to x128, rounded up
#define MAXMT (SLOTCAP / TILE)

// ---------- helpers ----------
__device__ __forceinline__ u16 f2bf(float f) {
  union { float f; u32 u; } v; v.f = f;
  u32 r = v.u + 0x7fffu + ((v.u >> 16) & 1u);   // RNE
  return (u16)(r >> 16);
}

__device__ __forceinline__ void gl_lds16(const void* g, void* l) {
  __builtin_amdgcn_global_load_lds(
      (__attribute__((address_space(1))) u32*)(uintptr_t)g,
      (__attribute__((address_space(3))) u32*)l, 16, 0, 0);
}

__device__ __forceinline__ float gelu_t(float x) {
  float u = 0.7978845608028654f * (x + 0.044715f * x * x * x);
  float e = __expf(2.0f * u);
  float th = 1.0f - 2.0f / (e + 1.0f);          // overflow-safe tanh
  return 0.5f * x * (1.0f + th);
}

// ---------- x -> bf16 ----------
__global__ void k_cvt_x(const float* __restrict__ x, u16* __restrict__ xb) {
  int i = blockIdx.x * blockDim.x + threadIdx.x;
  float4 v = ((const float4*)x)[i];
  uint2 p;
  p.x = (u32)f2bf(v.x) | ((u32)f2bf(v.y) << 16);
  p.y = (u32)f2bf(v.z) | ((u32)f2bf(v.w) << 16);
  ((uint2*)xb)[i] = p;
}

// ---------- weight transpose + convert: in [E][R][C] f32 -> out [E][C][R] bf16 ----------
__global__ void k_transpose_bf16(const float* __restrict__ in, u16* __restrict__ out,
                                 int R, int C) {
  __shared__ float tile[32][33];
  int e = blockIdx.z;
  const float* src = in + (size_t)e * R * C;
  u16* dst = out + (size_t)e * R * C;
  int c0 = blockIdx.x * 32, r0 = blockIdx.y * 32;
  int tx = threadIdx.x, ty = threadIdx.y;
#pragma unroll
  for (int i = 0; i < 4; i++)
    tile[ty + i * 8][tx] = src[(size_t)(r0 + ty + i * 8) * C + c0 + tx];
  __syncthreads();
#pragma unroll
  for (int i = 0; i < 4; i++)
    dst[(size_t)(c0 + ty + i * 8) * R + r0 + tx] = f2bf(tile[tx][ty + i * 8]);
}

// ---------- phase 1: per-token top-4 (no atomics) ----------
__global__ void k_topk(const float* __restrict__ x, const float* __restrict__ rw,
                       int* __restrict__ eid, float* __restrict__ tw) {
  int token = blockIdx.x * 4 + (threadIdx.x >> 6);
  int lane = threadIdx.x & 63;
  const float* xr = x + (size_t)token * DDIM;
  float p[NEXP];
#pragma unroll
  for (int e = 0; e < NEXP; e++) p[e] = 0.f;
  for (int it = 0; it < DDIM / 64; ++it) {
    int j = it * 64 + lane;
    float xj = xr[j];
    const float* r = rw + (size_t)j * NEXP;
    float4 a = *(const float4*)r;
    float4 b = *(const float4*)(r + 4);
    p[0] += xj * a.x; p[1] += xj * a.y; p[2] += xj * a.z; p[3] += xj * a.w;
    p[4] += xj * b.x; p[5] += xj * b.y; p[6] += xj * b.z; p[7] += xj * b.w;
  }
#pragma unroll
  for (int off = 32; off; off >>= 1) {
#pragma unroll
    for (int e = 0; e < NEXP; e++) p[e] += __shfl_xor(p[e], off);
  }
  unsigned used = 0;
  int idx[KSEL]; float lg[KSEL];
#pragma unroll
  for (int k = 0; k < KSEL; k++) {
    float bv = -1e30f; int bi = 0;
#pragma unroll
    for (int e = 0; e < NEXP; e++)
      if (!((used >> e) & 1) && p[e] > bv) { bv = p[e]; bi = e; }
    used |= 1u << bi; idx[k] = bi; lg[k] = bv;
  }
  float wv[KSEL]; float wsum = 0.f;
#pragma unroll
  for (int k = 0; k < KSEL; k++) { wv[k] = __expf(lg[k] - lg[0]); wsum += wv[k]; }
  float inv = 1.f / wsum;
  if (lane < KSEL) {
    eid[token * KSEL + lane] = idx[lane];
    tw[token * KSEL + lane] = wv[lane] * inv;
  }
}

// ---------- phase 2: per-expert counts -> 128-padded offsets ----------
__global__ void k_offsets(const int* __restrict__ eid, int* __restrict__ poff) {
  __shared__ int cnt[NEXP];
  if (threadIdx.x < NEXP) cnt[threadIdx.x] = 0;
  __syncthreads();
  int l0=0,l1=0,l2=0,l3=0,l4=0,l5=0,l6=0,l7=0;
  for (int i = threadIdx.x; i < NTOK * KSEL; i += 256) {
    int v = eid[i];
    l0 += (v == 0); l1 += (v == 1); l2 += (v == 2); l3 += (v == 3);
    l4 += (v == 4); l5 += (v == 5); l6 += (v == 6); l7 += (v == 7);
  }
  atomicAdd(&cnt[0], l0); atomicAdd(&cnt[1], l1);
  atomicAdd(&cnt[2], l2); atomicAdd(&cnt[3], l3);
  atomicAdd(&cnt[4], l4); atomicAdd(&cnt[5], l5);
  atomicAdd(&cnt[6], l6); atomicAdd(&cnt[7], l7);
  __syncthreads();
  if (threadIdx.x == 0) {
    int acc = 0;
#pragma unroll
    for (int e = 0; e < NEXP; e++) {
      poff[e] = acc;
      acc += ((cnt[e] + TILE - 1) / TILE) * TILE;
    }
    poff[NEXP] = acc;
  }
}

// ---------- phase 3: deterministic scan-scatter into combined slot list ----------
__global__ void k_scatter(const int* __restrict__ eid, const float* __restrict__ tw,
                          const int* __restrict__ poff,
                          int* __restrict__ tok_cmb, float* __restrict__ w_cmb) {
  int e = blockIdx.x;
  int base = poff[e];
  __shared__ int wave_tot[16];
  __shared__ int running;
  if (threadIdx.x == 0) running = 0;
  __syncthreads();
  int lane = threadIdx.x & 63, wave = threadIdx.x >> 6;
  for (int c = 0; c < NTOK * KSEL; c += 1024) {
    int i = c + threadIdx.x;
    bool f = (eid[i] == e);
    unsigned long long m = __ballot(f);
    int wexcl = __popcll(m & ((1ull << lane) - 1ull));
    if (lane == 0) wave_tot[wave] = __popcll(m);
    __syncthreads();
    int rbase = running;
    int wbase = 0;
    for (int wv = 0; wv < wave; wv++) wbase += wave_tot[wv];
    if (f) {
      int pos = base + rbase + wbase + wexcl;
      tok_cmb[pos] = i >> 2;
      w_cmb[pos] = tw[i];
    }
    __syncthreads();
    if (threadIdx.x == 0) {
      int s = 0;
#pragma unroll
      for (int wv = 0; wv < 16; wv++) s += wave_tot[wv];
      running = rbase + s;
    }
    __syncthreads();
  }
}

// ---------- grouped GEMM (m97-lineage 128x128 tile, 4 waves, BK=32) ----------
// IS_UP:  A=xb (rows gathered via tok_cmb), B=upbT[e] [H][D], epilogue gelu -> act bf16
// !IS_UP: A=act (linear by local row), B=downbT[e] [D][H], epilogue atomicAdd(w*acc) into out
template <bool IS_UP>
__global__ __launch_bounds__(256) void k_moe_gemm(
    const u16* __restrict__ A, const u16* __restrict__ Bbase,
    const int* __restrict__ tok_cmb, const float* __restrict__ w_cmb,
    const int* __restrict__ poff,
    u16* __restrict__ act, float* __restrict__ out, int e_fixed) {
  const int mtile = blockIdx.y;
  const int pbase = (e_fixed >= 0) ? poff[e_fixed] : 0;
  const int pend = (e_fixed >= 0) ? poff[e_fixed + 1] : poff[NEXP];
  const int slot0 = pbase + mtile * TILE;
  if (slot0 >= pend) return;
  int e;
  if (e_fixed >= 0) {
    e = e_fixed;
  } else {
    e = 0;
#pragma unroll
    for (int i = 1; i < NEXP; i++) e += (slot0 >= poff[i]);
  }
  const int ntile = blockIdx.x;
  const int K = IS_UP ? DDIM : HDIM;
  const u16* B = Bbase + (size_t)e * HDIM * DDIM;

  __shared__ u16 As[TILE * BK];
  __shared__ u16 Bs[TILE * BK];

  const int t = threadIdx.x, lane = t & 63, wave = t >> 6;
  const int ar = t >> 2, akb = (t & 3) * 8;
  int row0, row1;
  if (IS_UP) {
    row0 = tok_cmb[slot0 + ar];
    row1 = tok_cmb[slot0 + ar + 64];
  } else {
    row0 = mtile * TILE + ar;       // local act row
    row1 = row0 + 64;
  }
  const u16* gA0 = A + (size_t)row0 * K + akb;
  const u16* gA1 = A + (size_t)row1 * K + akb;
  const int bn = ntile * TILE + ar;
  const u16* gB0 = B + (size_t)bn * K + akb;
  const u16* gB1 = gB0 + (size_t)64 * K;

  u16* AsW = As + wave * 512;
  u16* BsW = Bs + wave * 512;

  f32x4 acc[4][4];
#pragma unroll
  for (int m = 0; m < 4; m++)
#pragma unroll
    for (int n = 0; n < 4; n++) acc[m][n] = (f32x4){0.f, 0.f, 0.f, 0.f};

  const int wm = wave >> 1, wn = wave & 1;
  const int fr = lane & 15, fk = (lane >> 4) * 8;

  for (int k0 = 0; k0 < K; k0 += BK) {
    gl_lds16(gA0 + k0, AsW);
    gl_lds16(gA1 + k0, AsW + 2048);
    gl_lds16(gB0 + k0, BsW);
    gl_lds16(gB1 + k0, BsW + 2048);
    __syncthreads();
    bf16x8 a[4], b[4];
#pragma unroll
    for (int m = 0; m < 4; m++) a[m] = *(const bf16x8*)&As[(wm * 64 + m * 16 + fr) * BK + fk];
#pragma unroll
    for (int n = 0; n < 4; n++) b[n] = *(const bf16x8*)&Bs[(wn * 64 + n * 16 + fr) * BK + fk];
#pragma unroll
    for (int m = 0; m < 4; m++)
#pragma unroll
      for (int n = 0; n < 4; n++)
        acc[m][n] = __builtin_amdgcn_mfma_f32_16x16x32_bf16(a[m], b[n], acc[m][n], 0, 0, 0);
    __syncthreads();
  }

  if (IS_UP) {
#pragma unroll
    for (int m = 0; m < 4; m++) {
#pragma unroll
      for (int j = 0; j < 4; j++) {
        int r = wm * 64 + m * 16 + (lane >> 4) * 4 + j;
        size_t rowoff = (size_t)(mtile * TILE + r) * HDIM + (size_t)ntile * TILE;
#pragma unroll
        for (int n = 0; n < 4; n++) {
          int c = wn * 64 + n * 16 + fr;
          act[rowoff + c] = f2bf(gelu_t(acc[m][n][j]));
        }
      }
    }
  } else {
#pragma unroll
    for (int m = 0; m < 4; m++) {
#pragma unroll
      for (int j = 0; j < 4; j++) {
        int r = wm * 64 + m * 16 + (lane >> 4) * 4 + j;
        int slot = slot0 + r;            // pad slots have w=0 -> adds 0
        int tok = tok_cmb[slot];
        float w = w_cmb[slot];
        float* orow = out + (size_t)tok * DDIM + (size_t)ntile * TILE;
#pragma unroll
        for (int n = 0; n < 4; n++) {
          int c = wn * 64 + n * 16 + fr;
          atomicAdd(&orow[c], w * acc[m][n][j]);
        }
      }
    }
  }
}

// ---------- launch ----------
extern "C" void kernel_launch(void* const* d_in, const int* in_sizes, int n_in,
                              void* d_out, int out_size, void* d_ws, size_t ws_size,
                              hipStream_t stream) {
  const float* x  = (const float*)d_in[0];
  const float* rw = (const float*)d_in[1];
  const float* up = (const float*)d_in[2];
  const float* dw = (const float*)d_in[3];
  float* out = (float*)d_out;

  char* ws = (char*)d_ws;
  size_t off = 0;
  u16* xb = (u16*)(ws + off);      off += (size_t)NTOK * DDIM * 2;          // 16 MiB
  u16* upbT = (u16*)(ws + off);    off += (size_t)NEXP * HDIM * DDIM * 2;   // 64 MiB
  u16* downbT = (u16*)(ws + off);  off += (size_t)NEXP * DDIM * HDIM * 2;   // 64 MiB
  int* eid = (int*)(ws + off);     off += (size_t)NTOK * KSEL * 4;
  float* tw = (float*)(ws + off);  off += (size_t)NTOK * KSEL * 4;
  int* poff = (int*)(ws + off);    off += 64;
  int* tok_cmb = (int*)(ws + off); off += (size_t)SLOTCAP * 4;
  float* w_cmb = (float*)(ws + off); off += (size_t)SLOTCAP * 4;
  u16* act = (u16*)(ws + off);
  size_t need_big = off + (size_t)SLOTCAP * HDIM * 2;        // ~428 MB
  // fallback act: one expert (<=8192 padded slots) at a time     ~208.5 MB
  const bool big = (ws_size >= need_big);

  hipMemsetAsync(d_out, 0, (size_t)NTOK * DDIM * 4, stream);
  hipMemsetAsync(tok_cmb, 0, (size_t)SLOTCAP * 8, stream);   // tok_cmb + w_cmb (adjacent)

  k_cvt_x<<<dim3(NTOK * DDIM / 4 / 256), dim3(256), 0, stream>>>(x, xb);
  k_transpose_bf16<<<dim3(HDIM / 32, DDIM / 32, NEXP), dim3(32, 8), 0, stream>>>(up, upbT, DDIM, HDIM);
  k_transpose_bf16<<<dim3(DDIM / 32, HDIM / 32, NEXP), dim3(32, 8), 0, stream>>>(dw, downbT, HDIM, DDIM);
  k_topk<<<dim3(NTOK / 4), dim3(256), 0, stream>>>(x, rw, eid, tw);
  k_offsets<<<dim3(1), dim3(256), 0, stream>>>(eid, poff);
  k_scatter<<<dim3(NEXP), dim3(1024), 0, stream>>>(eid, tw, poff, tok_cmb, w_cmb);

  if (big) {
    k_moe_gemm<true><<<dim3(HDIM / TILE, MAXMT), dim3(256), 0, stream>>>(
        xb, upbT, tok_cmb, w_cmb, poff, act, out, -1);
    k_moe_gemm<false><<<dim3(DDIM / TILE, MAXMT), dim3(256), 0, stream>>>(
        act, downbT, tok_cmb, w_cmb, poff, act, out, -1);
  } else {
    for (int e = 0; e < NEXP; e++) {
      k_moe_gemm<true><<<dim3(HDIM / TILE, NTOK / TILE), dim3(256), 0, stream>>>(
          xb, upbT, tok_cmb, w_cmb, poff, act, out, e);
      k_moe_gemm<false><<<dim3(DDIM / TILE, NTOK / TILE), dim3(256), 0, stream>>>(
          act, downbT, tok_cmb, w_cmb, poff, act, out, e);
    }
  }
}